// Round 1
// baseline (1809.250 us; speedup 1.0000x reference)
//
#include <hip/hip_runtime.h>
#include <hip/hip_bf16.h>

#define B_    2
#define LSEQ  1024
#define DM    1024
#define DI    2048
#define DTR   64
#define DS    16
#define MROWS 2048   // B_*LSEQ rows per direction

__device__ __forceinline__ float softplus_f(float x) {
  // numerically stable log1p(exp(x))
  return fmaxf(x, 0.f) + log1pf(__expf(-fabsf(x)));
}

// ---------------------------------------------------------------------------
// 128x128 tile fp32 GEMM, 256 threads, 8x8 per thread, BK=16.
// Requires: M % 128 == 0, N % 128 == 0, K % 16 == 0 (true for all uses here).
// dir = blockIdx.z selects per-direction A/W/bias/C via strides.
// revA/revC: reverse row index within each length-LSEQ group when dir==1.
// colOffDir: column offset = dir*colOffDir on store (for concat buffer).
// ACT: 0 = none, 1 = +bias, 2 = softplus(x + bias)
// ---------------------------------------------------------------------------
template<int ACT>
__global__ __launch_bounds__(256)
void gemm128(const float* __restrict__ A, long sAd, int lda, int revA,
             const float* __restrict__ W, long sWd,
             const float* __restrict__ bias, int sBd,
             float* __restrict__ C, long sCd, int ldc, int revC, int colOffDir,
             int N, int K)
{
  const int dir = blockIdx.z;
  A += (long)dir * sAd;
  W += (long)dir * sWd;
  C += (long)dir * sCd;
  const float* bp = bias ? (bias + (long)dir * sBd) : nullptr;

  const int m0 = blockIdx.y * 128;
  const int n0 = blockIdx.x * 128;

  __shared__ float sA[16][132];
  __shared__ float sB[16][132];

  const int t  = threadIdx.x;
  const int tx = t & 15, ty = t >> 4;
  const int ar = t >> 2, ak = (t & 3) << 2;   // A tile: 128 rows x 16 k
  const int wr = t >> 5, wc = (t & 31) << 2;  // W tile: 16 k x 128 n

  float acc[8][8];
  #pragma unroll
  for (int i = 0; i < 8; i++)
    #pragma unroll
    for (int j = 0; j < 8; j++) acc[i][j] = 0.f;

  for (int k0 = 0; k0 < K; k0 += 16) {
    #pragma unroll
    for (int i = 0; i < 2; i++) {
      const int mm = m0 + ar + (i << 6);
      const int mr = (revA && dir) ? ((mm & ~(LSEQ - 1)) | (LSEQ - 1 - (mm & (LSEQ - 1)))) : mm;
      const float4 v = *(const float4*)(A + (long)mr * lda + (k0 + ak));
      sA[ak + 0][ar + (i << 6)] = v.x;
      sA[ak + 1][ar + (i << 6)] = v.y;
      sA[ak + 2][ar + (i << 6)] = v.z;
      sA[ak + 3][ar + (i << 6)] = v.w;
    }
    #pragma unroll
    for (int i = 0; i < 2; i++) {
      const int kk = k0 + wr + (i << 3);
      const float4 v = *(const float4*)(W + (long)kk * N + (n0 + wc));
      *(float4*)&sB[wr + (i << 3)][wc] = v;
    }
    __syncthreads();

    #pragma unroll
    for (int kk = 0; kk < 16; kk++) {
      float a[8], b[8];
      *(float4*)&a[0] = *(const float4*)&sA[kk][(ty << 3) + 0];
      *(float4*)&a[4] = *(const float4*)&sA[kk][(ty << 3) + 4];
      *(float4*)&b[0] = *(const float4*)&sB[kk][(tx << 3) + 0];
      *(float4*)&b[4] = *(const float4*)&sB[kk][(tx << 3) + 4];
      #pragma unroll
      for (int i = 0; i < 8; i++)
        #pragma unroll
        for (int j = 0; j < 8; j++)
          acc[i][j] += a[i] * b[j];
    }
    __syncthreads();
  }

  const int colOff = dir * colOffDir;
  #pragma unroll
  for (int i = 0; i < 8; i++) {
    const int mm = m0 + (ty << 3) + i;
    const int mr = (revC && dir) ? ((mm & ~(LSEQ - 1)) | (LSEQ - 1 - (mm & (LSEQ - 1)))) : mm;
    float* crow = C + (long)mr * ldc + colOff + n0 + (tx << 3);
    float v[8];
    #pragma unroll
    for (int j = 0; j < 8; j++) {
      float vv = acc[i][j];
      if (ACT >= 1) vv += bp[n0 + (tx << 3) + j];
      if (ACT == 2) vv = softplus_f(vv);
      v[j] = vv;
    }
    *(float4*)(crow + 0) = make_float4(v[0], v[1], v[2], v[3]);
    *(float4*)(crow + 4) = make_float4(v[4], v[5], v[6], v[7]);
  }
}

// ---------------------------------------------------------------------------
// 32x32 tile fp32 GEMM for the small-N xp projection (N=96).
// Requires M,K % 32 == 0 and N % 32 == 0.
// ---------------------------------------------------------------------------
__global__ __launch_bounds__(256)
void gemm32(const float* __restrict__ A, long sAd, int lda,
            const float* __restrict__ W, long sWd,
            float* __restrict__ C, long sCd, int ldc,
            int N, int K)
{
  const int dir = blockIdx.z;
  A += (long)dir * sAd;
  W += (long)dir * sWd;
  C += (long)dir * sCd;

  const int m0 = blockIdx.y * 32;
  const int n0 = blockIdx.x * 32;

  __shared__ float sA[32][33];
  __shared__ float sB[32][36];

  const int t  = threadIdx.x;
  const int lr = t >> 3, lc = (t & 7) << 2;
  const int tx = t & 15, ty = t >> 4;

  float acc[2][2] = {{0.f, 0.f}, {0.f, 0.f}};

  for (int k0 = 0; k0 < K; k0 += 32) {
    const float4 va = *(const float4*)(A + (long)(m0 + lr) * lda + (k0 + lc));
    sA[lc + 0][lr] = va.x;
    sA[lc + 1][lr] = va.y;
    sA[lc + 2][lr] = va.z;
    sA[lc + 3][lr] = va.w;
    const float4 vw = *(const float4*)(W + (long)(k0 + lr) * N + (n0 + lc));
    *(float4*)&sB[lr][lc] = vw;
    __syncthreads();

    #pragma unroll
    for (int kk = 0; kk < 32; kk++) {
      const float a0 = sA[kk][ty * 2 + 0];
      const float a1 = sA[kk][ty * 2 + 1];
      const float b0 = sB[kk][tx * 2 + 0];
      const float b1 = sB[kk][tx * 2 + 1];
      acc[0][0] += a0 * b0;
      acc[0][1] += a0 * b1;
      acc[1][0] += a1 * b0;
      acc[1][1] += a1 * b1;
    }
    __syncthreads();
  }

  #pragma unroll
  for (int i = 0; i < 2; i++)
    #pragma unroll
    for (int j = 0; j < 2; j++)
      C[(long)(m0 + ty * 2 + i) * ldc + n0 + tx * 2 + j] = acc[i][j];
}

// ---------------------------------------------------------------------------
// Depthwise causal conv (D_CONV=4) + bias + SiLU.  xz cols [0,DI) are xi.
// One thread per float4 of channels. grid covers 2 * MROWS * DI/4 elements.
// ---------------------------------------------------------------------------
__global__ __launch_bounds__(256)
void conv_silu_k(const float* __restrict__ xz, float* __restrict__ xc,
                 const float* __restrict__ cw, const float* __restrict__ cb)
{
  const long idx = (long)blockIdx.x * blockDim.x + threadIdx.x; // 2*2048*512
  const int d4  = (int)(idx & 511);
  const int m   = (int)((idx >> 9) & 2047);
  const int dir = (int)(idx >> 20);
  const int l = m & (LSEQ - 1);
  const int d = d4 << 2;

  const float* xzp = xz + ((long)dir * MROWS + m) * 4096 + d;
  const float* w   = cw + ((long)dir * DI + d) * 4;

  float4 wv0 = *(const float4*)(w + 0);
  float4 wv1 = *(const float4*)(w + 4);
  float4 wv2 = *(const float4*)(w + 8);
  float4 wv3 = *(const float4*)(w + 12);

  float4 acc = *(const float4*)(cb + (long)dir * DI + d);

  #pragma unroll
  for (int j = 0; j < 4; j++) {
    const int lj = l - 3 + j;
    if (lj >= 0) {
      const float4 xv = *(const float4*)(xzp + (long)(j - 3) * 4096);
      acc.x += xv.x * ((const float*)&wv0)[j];
      acc.y += xv.y * ((const float*)&wv1)[j];
      acc.z += xv.z * ((const float*)&wv2)[j];
      acc.w += xv.w * ((const float*)&wv3)[j];
    }
  }

  float4 o;
  o.x = acc.x / (1.f + __expf(-acc.x));
  o.y = acc.y / (1.f + __expf(-acc.y));
  o.z = acc.z / (1.f + __expf(-acc.z));
  o.w = acc.w / (1.f + __expf(-acc.w));
  *(float4*)(xc + ((long)dir * MROWS + m) * DI + d) = o;
}

// ---------------------------------------------------------------------------
// Sequential selective scan. One thread per (dir, b, d) chain, 16 states in
// registers.  B/C rows staged in LDS in chunks of 64 steps.  Fuses the
// D-skip and SiLU(z) gate and writes the result in-place over xc (=> ymul).
// ---------------------------------------------------------------------------
__global__ __launch_bounds__(256)
void scan_k(const float* __restrict__ dt, const float* __restrict__ dbc,
            float* __restrict__ xc, const float* __restrict__ xz,
            const float* __restrict__ A_log, const float* __restrict__ Dp)
{
  const int blk  = blockIdx.x;        // 32 blocks: dir(2) x b(2) x dblk(8)
  const int dblk = blk & 7;
  const int b    = (blk >> 3) & 1;
  const int dir  = blk >> 4;
  const int d    = (dblk << 8) + threadIdx.x;

  const long row0 = (long)dir * MROWS + (long)b * LSEQ;
  const float* dtp = dt + row0 * DI + d;
  float*       xcp = xc + row0 * DI + d;
  const float* zp  = xz + row0 * 4096 + DI + d;
  const float* bc  = dbc + row0 * 96;

  float Av[DS];
  #pragma unroll
  for (int n = 0; n < DS; n++)
    Av[n] = -__expf(A_log[((long)dir * DI + d) * DS + n]);
  const float Dd = Dp[(long)dir * DI + d];

  float h[DS];
  #pragma unroll
  for (int n = 0; n < DS; n++) h[n] = 0.f;

  __shared__ float sBC[64][32];

  for (int l0 = 0; l0 < LSEQ; l0 += 64) {
    __syncthreads();
    #pragma unroll
    for (int i = 0; i < 8; i++) {
      const int e = threadIdx.x * 8 + i;           // 0..2047
      sBC[e >> 5][e & 31] = bc[(long)(l0 + (e >> 5)) * 96 + 64 + (e & 31)];
    }
    __syncthreads();

    for (int li = 0; li < 64; li++) {
      const long l = l0 + li;
      const float dtv = dtp[l * DI];
      const float xv  = xcp[l * DI];
      const float zv  = zp[l * 4096];
      const float u = dtv * xv;
      float y = 0.f;
      #pragma unroll
      for (int n = 0; n < DS; n++) {
        const float dA = __expf(dtv * Av[n]);
        h[n] = h[n] * dA + u * sBC[li][n];
        y += h[n] * sBC[li][16 + n];
      }
      const float sig = 1.f / (1.f + __expf(-zv));
      xcp[l * DI] = (y + xv * Dd) * (zv * sig);
    }
  }
}

// ---------------------------------------------------------------------------
extern "C" void kernel_launch(void* const* d_in, const int* in_sizes, int n_in,
                              void* d_out, int out_size, void* d_ws, size_t ws_size,
                              hipStream_t stream)
{
  const float* x      = (const float*)d_in[0];
  const float* in_w   = (const float*)d_in[1];
  const float* conv_w = (const float*)d_in[2];
  const float* conv_b = (const float*)d_in[3];
  const float* xp_w   = (const float*)d_in[4];
  const float* dt_w   = (const float*)d_in[5];
  const float* dt_b   = (const float*)d_in[6];
  const float* A_log  = (const float*)d_in[7];
  const float* Dp     = (const float*)d_in[8];
  const float* out_w  = (const float*)d_in[9];
  const float* proj_w = (const float*)d_in[10];
  const float* proj_b = (const float*)d_in[11];
  float* out = (float*)d_out;

  // workspace layout (floats)
  float* ws  = (float*)d_ws;
  float* xz  = ws;                                  // 2*2048*4096 = 64 MB
  float* xc  = xz  + (long)2 * MROWS * 4096;        // 2*2048*2048 = 32 MB
  float* dbc = xc  + (long)2 * MROWS * DI;          // 2*2048*96
  float* dt  = dbc + (long)2 * MROWS * 96;          // 2*2048*2048 = 32 MB
  float* cat = dt  + (long)2 * MROWS * DI;          // 2048*2048   = 16 MB

  // G1: xz[dir] = (dir==1 ? reverse(x) : x) @ in_w[dir]        [2048 x 4096]
  hipLaunchKernelGGL(HIP_KERNEL_NAME(gemm128<0>), dim3(4096 / 128, 2048 / 128, 2), dim3(256), 0, stream,
                     x, (long)0, DM, 1,
                     in_w, (long)DM * 4096,
                     (const float*)nullptr, 0,
                     xz, (long)MROWS * 4096, 4096, 0, 0,
                     4096, DM);

  // conv + SiLU: xc = silu(causal_dwconv(xi) + conv_b)
  hipLaunchKernelGGL(conv_silu_k, dim3(8192), dim3(256), 0, stream,
                     xz, xc, conv_w, conv_b);

  // G2: dbc = xc @ xp_w  [2048 x 96]
  hipLaunchKernelGGL(gemm32, dim3(96 / 32, 2048 / 32, 2), dim3(256), 0, stream,
                     xc, (long)MROWS * DI, DI,
                     xp_w, (long)DI * 96,
                     dbc, (long)MROWS * 96, 96,
                     96, DI);

  // G3: dt = softplus(dbc[:, :64] @ dt_w + dt_b)  [2048 x 2048]
  hipLaunchKernelGGL(HIP_KERNEL_NAME(gemm128<2>), dim3(2048 / 128, 2048 / 128, 2), dim3(256), 0, stream,
                     dbc, (long)MROWS * 96, 96, 0,
                     dt_w, (long)DTR * DI,
                     dt_b, DI,
                     dt, (long)MROWS * DI, DI, 0, 0,
                     DI, DTR);

  // scan: xc <- (scan_y + xc*D) * silu(z)
  hipLaunchKernelGGL(scan_k, dim3(32), dim3(256), 0, stream,
                     dt, dbc, xc, xz, A_log, Dp);

  // G4: cat[:, dir*1024 + :] = ymul @ out_w[dir]  (rows reversed for dir 1)
  hipLaunchKernelGGL(HIP_KERNEL_NAME(gemm128<0>), dim3(1024 / 128, 2048 / 128, 2), dim3(256), 0, stream,
                     xc, (long)MROWS * DI, DI, 0,
                     out_w, (long)DI * DM,
                     (const float*)nullptr, 0,
                     cat, (long)0, 2048, 1, 1024,
                     DM, DI);

  // G5: out = cat @ proj_w + proj_b  [2048 x 1024]
  hipLaunchKernelGGL(HIP_KERNEL_NAME(gemm128<1>), dim3(1024 / 128, 2048 / 128, 1), dim3(256), 0, stream,
                     cat, (long)0, 2048, 0,
                     proj_w, (long)0,
                     proj_b, 0,
                     out, (long)0, DM, 0, 0,
                     DM, 2048);
}

// Round 2
// 1156.760 us; speedup vs baseline: 1.5641x; 1.5641x over previous
//
#include <hip/hip_runtime.h>
#include <hip/hip_bf16.h>

#define B_    2
#define LSEQ  1024
#define DM    1024
#define DI    2048
#define DTR   64
#define DS    16
#define MROWS 2048   // B_*LSEQ rows per direction
#define NCH   16     // scan chunks per sequence
#define CL    64     // steps per chunk (NCH*CL == LSEQ)

__device__ __forceinline__ float softplus_f(float x) {
  return fmaxf(x, 0.f) + log1pf(__expf(-fabsf(x)));
}

// ---------------------------------------------------------------------------
// 128x128 tile fp32 GEMM, 256 threads, 8x8 per thread, BK=16.
// dir = blockIdx.z selects per-direction A/W/bias/C via strides.
// revA/revC: reverse row index within each length-LSEQ group when dir==1.
// colOffDir: column offset = dir*colOffDir on store (for concat buffer).
// ACT: 0 = none, 1 = +bias, 2 = softplus(x + bias)
// ---------------------------------------------------------------------------
template<int ACT>
__global__ __launch_bounds__(256)
void gemm128(const float* __restrict__ A, long sAd, int lda, int revA,
             const float* __restrict__ W, long sWd,
             const float* __restrict__ bias, int sBd,
             float* __restrict__ C, long sCd, int ldc, int revC, int colOffDir,
             int N, int K)
{
  const int dir = blockIdx.z;
  A += (long)dir * sAd;
  W += (long)dir * sWd;
  C += (long)dir * sCd;
  const float* bp = bias ? (bias + (long)dir * sBd) : nullptr;

  const int m0 = blockIdx.y * 128;
  const int n0 = blockIdx.x * 128;

  __shared__ float sA[16][132];
  __shared__ float sB[16][132];

  const int t  = threadIdx.x;
  const int tx = t & 15, ty = t >> 4;
  const int ar = t >> 2, ak = (t & 3) << 2;
  const int wr = t >> 5, wc = (t & 31) << 2;

  float acc[8][8];
  #pragma unroll
  for (int i = 0; i < 8; i++)
    #pragma unroll
    for (int j = 0; j < 8; j++) acc[i][j] = 0.f;

  for (int k0 = 0; k0 < K; k0 += 16) {
    #pragma unroll
    for (int i = 0; i < 2; i++) {
      const int mm = m0 + ar + (i << 6);
      const int mr = (revA && dir) ? ((mm & ~(LSEQ - 1)) | (LSEQ - 1 - (mm & (LSEQ - 1)))) : mm;
      const float4 v = *(const float4*)(A + (long)mr * lda + (k0 + ak));
      sA[ak + 0][ar + (i << 6)] = v.x;
      sA[ak + 1][ar + (i << 6)] = v.y;
      sA[ak + 2][ar + (i << 6)] = v.z;
      sA[ak + 3][ar + (i << 6)] = v.w;
    }
    #pragma unroll
    for (int i = 0; i < 2; i++) {
      const int kk = k0 + wr + (i << 3);
      const float4 v = *(const float4*)(W + (long)kk * N + (n0 + wc));
      *(float4*)&sB[wr + (i << 3)][wc] = v;
    }
    __syncthreads();

    #pragma unroll
    for (int kk = 0; kk < 16; kk++) {
      float a[8], b[8];
      *(float4*)&a[0] = *(const float4*)&sA[kk][(ty << 3) + 0];
      *(float4*)&a[4] = *(const float4*)&sA[kk][(ty << 3) + 4];
      *(float4*)&b[0] = *(const float4*)&sB[kk][(tx << 3) + 0];
      *(float4*)&b[4] = *(const float4*)&sB[kk][(tx << 3) + 4];
      #pragma unroll
      for (int i = 0; i < 8; i++)
        #pragma unroll
        for (int j = 0; j < 8; j++)
          acc[i][j] += a[i] * b[j];
    }
    __syncthreads();
  }

  const int colOff = dir * colOffDir;
  #pragma unroll
  for (int i = 0; i < 8; i++) {
    const int mm = m0 + (ty << 3) + i;
    const int mr = (revC && dir) ? ((mm & ~(LSEQ - 1)) | (LSEQ - 1 - (mm & (LSEQ - 1)))) : mm;
    float* crow = C + (long)mr * ldc + colOff + n0 + (tx << 3);
    float v[8];
    #pragma unroll
    for (int j = 0; j < 8; j++) {
      float vv = acc[i][j];
      if (ACT >= 1) vv += bp[n0 + (tx << 3) + j];
      if (ACT == 2) vv = softplus_f(vv);
      v[j] = vv;
    }
    *(float4*)(crow + 0) = make_float4(v[0], v[1], v[2], v[3]);
    *(float4*)(crow + 4) = make_float4(v[4], v[5], v[6], v[7]);
  }
}

// ---------------------------------------------------------------------------
// 32x32 tile fp32 GEMM for the small-N xp projection (N=96).
// ---------------------------------------------------------------------------
__global__ __launch_bounds__(256)
void gemm32(const float* __restrict__ A, long sAd, int lda,
            const float* __restrict__ W, long sWd,
            float* __restrict__ C, long sCd, int ldc,
            int N, int K)
{
  const int dir = blockIdx.z;
  A += (long)dir * sAd;
  W += (long)dir * sWd;
  C += (long)dir * sCd;

  const int m0 = blockIdx.y * 32;
  const int n0 = blockIdx.x * 32;

  __shared__ float sA[32][33];
  __shared__ float sB[32][36];

  const int t  = threadIdx.x;
  const int lr = t >> 3, lc = (t & 7) << 2;
  const int tx = t & 15, ty = t >> 4;

  float acc[2][2] = {{0.f, 0.f}, {0.f, 0.f}};

  for (int k0 = 0; k0 < K; k0 += 32) {
    const float4 va = *(const float4*)(A + (long)(m0 + lr) * lda + (k0 + lc));
    sA[lc + 0][lr] = va.x;
    sA[lc + 1][lr] = va.y;
    sA[lc + 2][lr] = va.z;
    sA[lc + 3][lr] = va.w;
    const float4 vw = *(const float4*)(W + (long)(k0 + lr) * N + (n0 + lc));
    *(float4*)&sB[lr][lc] = vw;
    __syncthreads();

    #pragma unroll
    for (int kk = 0; kk < 32; kk++) {
      const float a0 = sA[kk][ty * 2 + 0];
      const float a1 = sA[kk][ty * 2 + 1];
      const float b0 = sB[kk][tx * 2 + 0];
      const float b1 = sB[kk][tx * 2 + 1];
      acc[0][0] += a0 * b0;
      acc[0][1] += a0 * b1;
      acc[1][0] += a1 * b0;
      acc[1][1] += a1 * b1;
    }
    __syncthreads();
  }

  #pragma unroll
  for (int i = 0; i < 2; i++)
    #pragma unroll
    for (int j = 0; j < 2; j++)
      C[(long)(m0 + ty * 2 + i) * ldc + n0 + tx * 2 + j] = acc[i][j];
}

// ---------------------------------------------------------------------------
// Depthwise causal conv (D_CONV=4) + bias + SiLU.
// ---------------------------------------------------------------------------
__global__ __launch_bounds__(256)
void conv_silu_k(const float* __restrict__ xz, float* __restrict__ xc,
                 const float* __restrict__ cw, const float* __restrict__ cb)
{
  const long idx = (long)blockIdx.x * blockDim.x + threadIdx.x;
  const int d4  = (int)(idx & 511);
  const int m   = (int)((idx >> 9) & 2047);
  const int dir = (int)(idx >> 20);
  const int l = m & (LSEQ - 1);
  const int d = d4 << 2;

  const float* xzp = xz + ((long)dir * MROWS + m) * 4096 + d;
  const float* w   = cw + ((long)dir * DI + d) * 4;

  float4 wv0 = *(const float4*)(w + 0);
  float4 wv1 = *(const float4*)(w + 4);
  float4 wv2 = *(const float4*)(w + 8);
  float4 wv3 = *(const float4*)(w + 12);

  float4 acc = *(const float4*)(cb + (long)dir * DI + d);

  #pragma unroll
  for (int j = 0; j < 4; j++) {
    const int lj = l - 3 + j;
    if (lj >= 0) {
      const float4 xv = *(const float4*)(xzp + (long)(j - 3) * 4096);
      acc.x += xv.x * ((const float*)&wv0)[j];
      acc.y += xv.y * ((const float*)&wv1)[j];
      acc.z += xv.z * ((const float*)&wv2)[j];
      acc.w += xv.w * ((const float*)&wv3)[j];
    }
  }

  float4 o;
  o.x = acc.x / (1.f + __expf(-acc.x));
  o.y = acc.y / (1.f + __expf(-acc.y));
  o.z = acc.z / (1.f + __expf(-acc.z));
  o.w = acc.w / (1.f + __expf(-acc.w));
  *(float4*)(xc + ((long)dir * MROWS + m) * DI + d) = o;
}

// ---------------------------------------------------------------------------
// Chunked parallel scan, pass 1: per-chunk local scan with h_init = 0.
// Stores local end-state E and chunk transition P[n] = exp(Av[n] * sum(dt)).
// Grid: 512 blocks = dir(2) x b(2) x dblk(8) x chunk(16), 256 threads (= d).
// ---------------------------------------------------------------------------
__global__ __launch_bounds__(256)
void scan_p1(const float* __restrict__ dt, const float* __restrict__ dbc,
             const float* __restrict__ xc, const float* __restrict__ A_log,
             float* __restrict__ Pbuf, float* __restrict__ Ebuf)
{
  const int blk  = blockIdx.x;
  const int c    = blk & 15;
  const int dblk = (blk >> 4) & 7;
  const int b    = (blk >> 7) & 1;
  const int dir  = blk >> 8;
  const int d    = (dblk << 8) + threadIdx.x;

  const long row0 = (long)dir * MROWS + (long)b * LSEQ + (long)c * CL;
  const float* dtp = dt + row0 * DI + d;
  const float* xcp = xc + row0 * DI + d;
  const float* bc  = dbc + row0 * 96;

  float Av[DS];
  #pragma unroll
  for (int n = 0; n < DS; n++)
    Av[n] = -__expf(A_log[((long)dir * DI + d) * DS + n]);

  __shared__ float sB[CL][DS];
  #pragma unroll
  for (int i = 0; i < 4; i++) {
    const int e = threadIdx.x * 4 + i;            // 0..1023 = 64 x 16
    sB[e >> 4][e & 15] = bc[(long)(e >> 4) * 96 + 64 + (e & 15)];
  }
  __syncthreads();

  float h[DS];
  #pragma unroll
  for (int n = 0; n < DS; n++) h[n] = 0.f;
  float sdt = 0.f;

  for (int li = 0; li < CL; li++) {
    const float dtv = dtp[(long)li * DI];
    const float xv  = xcp[(long)li * DI];
    const float u = dtv * xv;
    sdt += dtv;
    #pragma unroll
    for (int n = 0; n < DS; n++)
      h[n] = h[n] * __expf(dtv * Av[n]) + u * sB[li][n];
  }

  const long slot = ((long)((dir * 2 + b) * NCH + c)) * DS;
  #pragma unroll
  for (int n = 0; n < DS; n++) Ebuf[(slot + n) * DI + d] = h[n];
  #pragma unroll
  for (int n = 0; n < DS; n++) Pbuf[(slot + n) * DI + d] = __expf(Av[n] * sdt);
}

// ---------------------------------------------------------------------------
// Pass 2: sequential combine over the 16 chunks per (dir,b,d).
// Writes each chunk's true h_init OVER Pbuf (read P/E first, then overwrite).
// Grid: 32 blocks = dir(2) x b(2) x dblk(8), 256 threads.
// ---------------------------------------------------------------------------
__global__ __launch_bounds__(256)
void scan_p2(float* __restrict__ Pbuf, const float* __restrict__ Ebuf)
{
  const int blk  = blockIdx.x;
  const int dblk = blk & 7;
  const int b    = (blk >> 3) & 1;
  const int dir  = blk >> 4;
  const int d    = (dblk << 8) + threadIdx.x;

  float h[DS];
  #pragma unroll
  for (int n = 0; n < DS; n++) h[n] = 0.f;

  for (int c = 0; c < NCH; c++) {
    const long slot = ((long)((dir * 2 + b) * NCH + c)) * DS;
    float p[DS], e[DS];
    #pragma unroll
    for (int n = 0; n < DS; n++) p[n] = Pbuf[(slot + n) * DI + d];
    #pragma unroll
    for (int n = 0; n < DS; n++) e[n] = Ebuf[(slot + n) * DI + d];
    #pragma unroll
    for (int n = 0; n < DS; n++) Pbuf[(slot + n) * DI + d] = h[n];  // h_init
    #pragma unroll
    for (int n = 0; n < DS; n++) h[n] = p[n] * h[n] + e[n];
  }
}

// ---------------------------------------------------------------------------
// Pass 3: replay each chunk from its true h_init, emit y, fuse D-skip and
// SiLU(z) gate; writes result in place over xc.
// ---------------------------------------------------------------------------
__global__ __launch_bounds__(256)
void scan_p3(const float* __restrict__ dt, const float* __restrict__ dbc,
             float* __restrict__ xc, const float* __restrict__ xz,
             const float* __restrict__ A_log, const float* __restrict__ Dp,
             const float* __restrict__ Hbuf)
{
  const int blk  = blockIdx.x;
  const int c    = blk & 15;
  const int dblk = (blk >> 4) & 7;
  const int b    = (blk >> 7) & 1;
  const int dir  = blk >> 8;
  const int d    = (dblk << 8) + threadIdx.x;

  const long row0 = (long)dir * MROWS + (long)b * LSEQ + (long)c * CL;
  const float* dtp = dt + row0 * DI + d;
  float*       xcp = xc + row0 * DI + d;
  const float* zp  = xz + row0 * 4096 + DI + d;
  const float* bc  = dbc + row0 * 96;

  float Av[DS];
  #pragma unroll
  for (int n = 0; n < DS; n++)
    Av[n] = -__expf(A_log[((long)dir * DI + d) * DS + n]);
  const float Dd = Dp[(long)dir * DI + d];

  const long slot = ((long)((dir * 2 + b) * NCH + c)) * DS;
  float h[DS];
  #pragma unroll
  for (int n = 0; n < DS; n++) h[n] = Hbuf[(slot + n) * DI + d];

  __shared__ float sBC[CL][32];
  #pragma unroll
  for (int i = 0; i < 8; i++) {
    const int e = threadIdx.x * 8 + i;            // 0..2047 = 64 x 32
    sBC[e >> 5][e & 31] = bc[(long)(e >> 5) * 96 + 64 + (e & 31)];
  }
  __syncthreads();

  for (int li = 0; li < CL; li++) {
    const float dtv = dtp[(long)li * DI];
    const float xv  = xcp[(long)li * DI];
    const float zv  = zp[(long)li * 4096];
    const float u = dtv * xv;
    float y = 0.f;
    #pragma unroll
    for (int n = 0; n < DS; n++) {
      const float dA = __expf(dtv * Av[n]);
      h[n] = h[n] * dA + u * sBC[li][n];
      y += h[n] * sBC[li][16 + n];
    }
    const float sig = 1.f / (1.f + __expf(-zv));
    xcp[(long)li * DI] = (y + xv * Dd) * (zv * sig);
  }
}

// ---------------------------------------------------------------------------
extern "C" void kernel_launch(void* const* d_in, const int* in_sizes, int n_in,
                              void* d_out, int out_size, void* d_ws, size_t ws_size,
                              hipStream_t stream)
{
  const float* x      = (const float*)d_in[0];
  const float* in_w   = (const float*)d_in[1];
  const float* conv_w = (const float*)d_in[2];
  const float* conv_b = (const float*)d_in[3];
  const float* xp_w   = (const float*)d_in[4];
  const float* dt_w   = (const float*)d_in[5];
  const float* dt_b   = (const float*)d_in[6];
  const float* A_log  = (const float*)d_in[7];
  const float* Dp     = (const float*)d_in[8];
  const float* out_w  = (const float*)d_in[9];
  const float* proj_w = (const float*)d_in[10];
  const float* proj_b = (const float*)d_in[11];
  float* out = (float*)d_out;

  // workspace layout (floats)
  float* ws  = (float*)d_ws;
  float* xz  = ws;                                  // 2*2048*4096
  float* xc  = xz  + (long)2 * MROWS * 4096;        // 2*2048*2048
  float* dbc = xc  + (long)2 * MROWS * DI;          // 2*2048*96
  float* dt  = dbc + (long)2 * MROWS * 96;          // 2*2048*2048
  float* cat = dt  + (long)2 * MROWS * DI;          // 2048*2048
  float* Pbuf = cat + (long)MROWS * 2048;           // 2*2*16*16*2048 = 8 MB
  float* Ebuf = Pbuf + (long)2 * B_ * NCH * DS * DI; // 8 MB

  // G1: xz[dir] = (dir==1 ? reverse(x) : x) @ in_w[dir]
  hipLaunchKernelGGL(HIP_KERNEL_NAME(gemm128<0>), dim3(4096 / 128, 2048 / 128, 2), dim3(256), 0, stream,
                     x, (long)0, DM, 1,
                     in_w, (long)DM * 4096,
                     (const float*)nullptr, 0,
                     xz, (long)MROWS * 4096, 4096, 0, 0,
                     4096, DM);

  // conv + SiLU
  hipLaunchKernelGGL(conv_silu_k, dim3(8192), dim3(256), 0, stream,
                     xz, xc, conv_w, conv_b);

  // G2: dbc = xc @ xp_w
  hipLaunchKernelGGL(gemm32, dim3(96 / 32, 2048 / 32, 2), dim3(256), 0, stream,
                     xc, (long)MROWS * DI, DI,
                     xp_w, (long)DI * 96,
                     dbc, (long)MROWS * 96, 96,
                     96, DI);

  // G3: dt = softplus(dbc[:, :64] @ dt_w + dt_b)
  hipLaunchKernelGGL(HIP_KERNEL_NAME(gemm128<2>), dim3(2048 / 128, 2048 / 128, 2), dim3(256), 0, stream,
                     dbc, (long)MROWS * 96, 96, 0,
                     dt_w, (long)DTR * DI,
                     dt_b, DI,
                     dt, (long)MROWS * DI, DI, 0, 0,
                     DI, DTR);

  // chunked parallel scan
  hipLaunchKernelGGL(scan_p1, dim3(512), dim3(256), 0, stream,
                     dt, dbc, xc, A_log, Pbuf, Ebuf);
  hipLaunchKernelGGL(scan_p2, dim3(32), dim3(256), 0, stream,
                     Pbuf, Ebuf);
  hipLaunchKernelGGL(scan_p3, dim3(512), dim3(256), 0, stream,
                     dt, dbc, xc, xz, A_log, Dp, Pbuf);

  // G4: cat[:, dir*1024 + :] = ymul @ out_w[dir]  (rows reversed for dir 1)
  hipLaunchKernelGGL(HIP_KERNEL_NAME(gemm128<0>), dim3(1024 / 128, 2048 / 128, 2), dim3(256), 0, stream,
                     xc, (long)MROWS * DI, DI, 0,
                     out_w, (long)DI * DM,
                     (const float*)nullptr, 0,
                     cat, (long)0, 2048, 1, 1024,
                     DM, DI);

  // G5: out = cat @ proj_w + proj_b
  hipLaunchKernelGGL(HIP_KERNEL_NAME(gemm128<1>), dim3(1024 / 128, 2048 / 128, 1), dim3(256), 0, stream,
                     cat, (long)0, 2048, 0,
                     proj_w, (long)0,
                     proj_b, 0,
                     out, (long)0, DM, 0, 0,
                     DM, 2048);
}

// Round 3
// 431.593 us; speedup vs baseline: 4.1920x; 2.6802x over previous
//
#include <hip/hip_runtime.h>
#include <hip/hip_bf16.h>

#define B_    2
#define LSEQ  1024
#define DM    1024
#define DI    2048
#define DTR   64
#define DS    16
#define MROWS 2048   // B_*LSEQ rows per direction
#define NCH   16     // scan chunks per sequence
#define CL    64     // steps per chunk

typedef __bf16 bf16x8 __attribute__((ext_vector_type(8)));
typedef short  s16x8  __attribute__((ext_vector_type(8)));
typedef float  f32x4  __attribute__((ext_vector_type(4)));

typedef __attribute__((address_space(1))) const unsigned int g_u32;
typedef __attribute__((address_space(3))) unsigned int l_u32;

__device__ __forceinline__ unsigned short f2bf(float f) {
  unsigned int u = __builtin_bit_cast(unsigned int, f);
  u += 0x7fffu + ((u >> 16) & 1u);           // RNE
  return (unsigned short)(u >> 16);
}

__device__ __forceinline__ void gload16(void* lds, const void* g) {
  __builtin_amdgcn_global_load_lds((g_u32*)g, (l_u32*)lds, 16, 0, 0);
}

__device__ __forceinline__ f32x4 mfma_bf16_16x16x32(s16x8 a, s16x8 b, f32x4 c) {
  return __builtin_amdgcn_mfma_f32_16x16x32_bf16(
      __builtin_bit_cast(bf16x8, a), __builtin_bit_cast(bf16x8, b), c, 0, 0, 0);
}

__device__ __forceinline__ float softplus_f(float x) {
  return fmaxf(x, 0.f) + log1pf(__expf(-fabsf(x)));
}

// ---------------------------------------------------------------------------
// bf16 MFMA GEMM, 128x128 tile, BK=32, 4 waves (m97 structure).
// A: bf16 row-major [M][K]; Bt: bf16 [N][K] (transposed weights).
// EPI: 0 = f32 store, 1 = f32 store + bias, 2 = bf16 store (revC + colOff)
// ---------------------------------------------------------------------------
template<int EPI>
__global__ __launch_bounds__(256)
void bgemm(const unsigned short* __restrict__ A, long sAd, int lda, int revA,
           const unsigned short* __restrict__ Bt, long sBd,
           const float* __restrict__ bias,
           void* __restrict__ C, long sCd, int ldc, int revC, int colOffDir,
           int K)
{
  const int dir = blockIdx.z;
  A  += (long)dir * sAd;
  Bt += (long)dir * sBd;

  const int m0 = blockIdx.y * 128;
  const int n0 = blockIdx.x * 128;

  __shared__ __align__(16) unsigned short sA[128 * 32];  // [row][k] 8KB
  __shared__ __align__(16) unsigned short sB[128 * 32];  // [n][k]   8KB

  const int t    = threadIdx.x;
  const int wave = t >> 6;
  const int lane = t & 63;
  const int l15  = lane & 15;
  const int l4   = lane >> 4;
  const int wr   = wave >> 1;   // wave tile 2x2, each 64x64
  const int wc   = wave & 1;

  f32x4 acc[4][4];
  #pragma unroll
  for (int i = 0; i < 4; i++)
    #pragma unroll
    for (int j = 0; j < 4; j++)
      acc[i][j] = f32x4{0.f, 0.f, 0.f, 0.f};

  for (int k0 = 0; k0 < K; k0 += 32) {
    // stage A tile: 512 chunks of 16B; LDS dest = uniform base + lane*16
    #pragma unroll
    for (int i = 0; i < 2; i++) {
      const int cb = (wave * 2 + i) * 64;
      const int ch = cb + lane;
      const int row = ch >> 2, kk = (ch & 3) << 3;
      const int mm = m0 + row;
      const int mr = (revA && dir) ? ((mm & ~(LSEQ - 1)) | (LSEQ - 1 - (mm & (LSEQ - 1)))) : mm;
      gload16(sA + (long)cb * 8, A + (long)mr * lda + k0 + kk);
    }
    // stage B tile
    #pragma unroll
    for (int i = 0; i < 2; i++) {
      const int cb = (wave * 2 + i) * 64;
      const int ch = cb + lane;
      const int n = ch >> 2, kk = (ch & 3) << 3;
      gload16(sB + (long)cb * 8, Bt + (long)(n0 + n) * K + k0 + kk);
    }
    __syncthreads();   // drains vmcnt before reads

    s16x8 af[4], bf[4];
    #pragma unroll
    for (int mi = 0; mi < 4; mi++)
      af[mi] = *(const s16x8*)(sA + ((wr * 64 + mi * 16 + l15) * 32 + l4 * 8));
    #pragma unroll
    for (int ni = 0; ni < 4; ni++)
      bf[ni] = *(const s16x8*)(sB + ((wc * 64 + ni * 16 + l15) * 32 + l4 * 8));
    #pragma unroll
    for (int mi = 0; mi < 4; mi++)
      #pragma unroll
      for (int ni = 0; ni < 4; ni++)
        acc[mi][ni] = mfma_bf16_16x16x32(af[mi], bf[ni], acc[mi][ni]);
    __syncthreads();
  }

  // epilogue: C/D layout col=lane&15, row=(lane>>4)*4+reg
  const int colOff = dir * colOffDir;
  float*          Cf = (float*)C + (long)dir * sCd;
  unsigned short* Cb = (unsigned short*)C + (long)dir * sCd;
  #pragma unroll
  for (int mi = 0; mi < 4; mi++) {
    #pragma unroll
    for (int r = 0; r < 4; r++) {
      const int mm = m0 + wr * 64 + mi * 16 + (l4 << 2) + r;
      const int mr = (revC && dir) ? ((mm & ~(LSEQ - 1)) | (LSEQ - 1 - (mm & (LSEQ - 1)))) : mm;
      #pragma unroll
      for (int ni = 0; ni < 4; ni++) {
        const int col = n0 + wc * 64 + ni * 16 + l15;
        float v = acc[mi][ni][r];
        if (EPI == 1) v += bias[col];
        if (EPI == 2) Cb[(long)mr * ldc + colOff + col] = f2bf(v);
        else          Cf[(long)mr * ldc + colOff + col] = v;
      }
    }
  }
}

// ---------------------------------------------------------------------------
// fp32 -> bf16 elementwise convert (4 elems/thread, exact grid)
// ---------------------------------------------------------------------------
__global__ __launch_bounds__(256)
void convert_bf16_k(const float* __restrict__ src, unsigned short* __restrict__ dst)
{
  const long i = ((long)blockIdx.x * 256 + threadIdx.x) << 2;
  const float4 v = *(const float4*)(src + i);
  ushort4 o;
  o.x = f2bf(v.x); o.y = f2bf(v.y); o.z = f2bf(v.z); o.w = f2bf(v.w);
  *(ushort4*)(dst + i) = o;
}

// ---------------------------------------------------------------------------
// fp32 [R][C] -> bf16 [C][R] transpose-convert, 32x32 tiles.
// ---------------------------------------------------------------------------
__global__ __launch_bounds__(256)
void transpose_bf16_k(const float* __restrict__ src, long sSd, int R, int C,
                      unsigned short* __restrict__ dst, long sDd)
{
  const int dir = blockIdx.z;
  src += (long)dir * sSd;
  dst += (long)dir * sDd;
  const int c0 = blockIdx.x * 32;
  const int r0 = blockIdx.y * 32;
  __shared__ float tile[32][33];
  const int t = threadIdx.x;
  const int lr = t >> 3, lc = (t & 7) << 2;
  const float4 v = *(const float4*)(src + (long)(r0 + lr) * C + c0 + lc);
  tile[lr][lc + 0] = v.x; tile[lr][lc + 1] = v.y;
  tile[lr][lc + 2] = v.z; tile[lr][lc + 3] = v.w;
  __syncthreads();
  const int oc = t >> 3, orr = (t & 7) << 2;
  ushort4 o;
  o.x = f2bf(tile[orr + 0][oc]);
  o.y = f2bf(tile[orr + 1][oc]);
  o.z = f2bf(tile[orr + 2][oc]);
  o.w = f2bf(tile[orr + 3][oc]);
  *(ushort4*)(dst + (long)(c0 + oc) * R + r0 + orr) = o;
}

// ---------------------------------------------------------------------------
// fp32 GEMMs kept for small ops (G3 dt-projection, G2 xp-projection)
// ---------------------------------------------------------------------------
template<int ACT>
__global__ __launch_bounds__(256)
void gemm128(const float* __restrict__ A, long sAd, int lda, int revA,
             const float* __restrict__ W, long sWd,
             const float* __restrict__ bias, int sBd,
             float* __restrict__ C, long sCd, int ldc, int revC, int colOffDir,
             int N, int K)
{
  const int dir = blockIdx.z;
  A += (long)dir * sAd;
  W += (long)dir * sWd;
  C += (long)dir * sCd;
  const float* bp = bias ? (bias + (long)dir * sBd) : nullptr;

  const int m0 = blockIdx.y * 128;
  const int n0 = blockIdx.x * 128;

  __shared__ float sA[16][132];
  __shared__ float sB[16][132];

  const int t  = threadIdx.x;
  const int tx = t & 15, ty = t >> 4;
  const int ar = t >> 2, ak = (t & 3) << 2;
  const int wrr = t >> 5, wcc = (t & 31) << 2;

  float acc[8][8];
  #pragma unroll
  for (int i = 0; i < 8; i++)
    #pragma unroll
    for (int j = 0; j < 8; j++) acc[i][j] = 0.f;

  for (int k0 = 0; k0 < K; k0 += 16) {
    #pragma unroll
    for (int i = 0; i < 2; i++) {
      const int mm = m0 + ar + (i << 6);
      const int mr = (revA && dir) ? ((mm & ~(LSEQ - 1)) | (LSEQ - 1 - (mm & (LSEQ - 1)))) : mm;
      const float4 v = *(const float4*)(A + (long)mr * lda + (k0 + ak));
      sA[ak + 0][ar + (i << 6)] = v.x;
      sA[ak + 1][ar + (i << 6)] = v.y;
      sA[ak + 2][ar + (i << 6)] = v.z;
      sA[ak + 3][ar + (i << 6)] = v.w;
    }
    #pragma unroll
    for (int i = 0; i < 2; i++) {
      const int kk = k0 + wrr + (i << 3);
      const float4 v = *(const float4*)(W + (long)kk * N + (n0 + wcc));
      *(float4*)&sB[wrr + (i << 3)][wcc] = v;
    }
    __syncthreads();

    #pragma unroll
    for (int kk = 0; kk < 16; kk++) {
      float a[8], b[8];
      *(float4*)&a[0] = *(const float4*)&sA[kk][(ty << 3) + 0];
      *(float4*)&a[4] = *(const float4*)&sA[kk][(ty << 3) + 4];
      *(float4*)&b[0] = *(const float4*)&sB[kk][(tx << 3) + 0];
      *(float4*)&b[4] = *(const float4*)&sB[kk][(tx << 3) + 4];
      #pragma unroll
      for (int i = 0; i < 8; i++)
        #pragma unroll
        for (int j = 0; j < 8; j++)
          acc[i][j] += a[i] * b[j];
    }
    __syncthreads();
  }

  const int colOff = dir * colOffDir;
  #pragma unroll
  for (int i = 0; i < 8; i++) {
    const int mm = m0 + (ty << 3) + i;
    const int mr = (revC && dir) ? ((mm & ~(LSEQ - 1)) | (LSEQ - 1 - (mm & (LSEQ - 1)))) : mm;
    float* crow = C + (long)mr * ldc + colOff + n0 + (tx << 3);
    float v[8];
    #pragma unroll
    for (int j = 0; j < 8; j++) {
      float vv = acc[i][j];
      if (ACT >= 1) vv += bp[n0 + (tx << 3) + j];
      if (ACT == 2) vv = softplus_f(vv);
      v[j] = vv;
    }
    *(float4*)(crow + 0) = make_float4(v[0], v[1], v[2], v[3]);
    *(float4*)(crow + 4) = make_float4(v[4], v[5], v[6], v[7]);
  }
}

__global__ __launch_bounds__(256)
void gemm32(const float* __restrict__ A, long sAd, int lda,
            const float* __restrict__ W, long sWd,
            float* __restrict__ C, long sCd, int ldc,
            int N, int K)
{
  const int dir = blockIdx.z;
  A += (long)dir * sAd;
  W += (long)dir * sWd;
  C += (long)dir * sCd;

  const int m0 = blockIdx.y * 32;
  const int n0 = blockIdx.x * 32;

  __shared__ float sA[32][33];
  __shared__ float sB[32][36];

  const int t  = threadIdx.x;
  const int lr = t >> 3, lc = (t & 7) << 2;
  const int tx = t & 15, ty = t >> 4;

  float acc[2][2] = {{0.f, 0.f}, {0.f, 0.f}};

  for (int k0 = 0; k0 < K; k0 += 32) {
    const float4 va = *(const float4*)(A + (long)(m0 + lr) * lda + (k0 + lc));
    sA[lc + 0][lr] = va.x;
    sA[lc + 1][lr] = va.y;
    sA[lc + 2][lr] = va.z;
    sA[lc + 3][lr] = va.w;
    const float4 vw = *(const float4*)(W + (long)(k0 + lr) * N + (n0 + lc));
    *(float4*)&sB[lr][lc] = vw;
    __syncthreads();

    #pragma unroll
    for (int kk = 0; kk < 32; kk++) {
      const float a0 = sA[kk][ty * 2 + 0];
      const float a1 = sA[kk][ty * 2 + 1];
      const float b0 = sB[kk][tx * 2 + 0];
      const float b1 = sB[kk][tx * 2 + 1];
      acc[0][0] += a0 * b0;
      acc[0][1] += a0 * b1;
      acc[1][0] += a1 * b0;
      acc[1][1] += a1 * b1;
    }
    __syncthreads();
  }

  #pragma unroll
  for (int i = 0; i < 2; i++)
    #pragma unroll
    for (int j = 0; j < 2; j++)
      C[(long)(m0 + ty * 2 + i) * ldc + n0 + tx * 2 + j] = acc[i][j];
}

// ---------------------------------------------------------------------------
// Depthwise causal conv (D_CONV=4) + bias + SiLU.
// ---------------------------------------------------------------------------
__global__ __launch_bounds__(256)
void conv_silu_k(const float* __restrict__ xz, float* __restrict__ xc,
                 const float* __restrict__ cw, const float* __restrict__ cb)
{
  const long idx = (long)blockIdx.x * blockDim.x + threadIdx.x;
  const int d4  = (int)(idx & 511);
  const int m   = (int)((idx >> 9) & 2047);
  const int dir = (int)(idx >> 20);
  const int l = m & (LSEQ - 1);
  const int d = d4 << 2;

  const float* xzp = xz + ((long)dir * MROWS + m) * 4096 + d;
  const float* w   = cw + ((long)dir * DI + d) * 4;

  float4 wv0 = *(const float4*)(w + 0);
  float4 wv1 = *(const float4*)(w + 4);
  float4 wv2 = *(const float4*)(w + 8);
  float4 wv3 = *(const float4*)(w + 12);

  float4 acc = *(const float4*)(cb + (long)dir * DI + d);

  #pragma unroll
  for (int j = 0; j < 4; j++) {
    const int lj = l - 3 + j;
    if (lj >= 0) {
      const float4 xv = *(const float4*)(xzp + (long)(j - 3) * 4096);
      acc.x += xv.x * ((const float*)&wv0)[j];
      acc.y += xv.y * ((const float*)&wv1)[j];
      acc.z += xv.z * ((const float*)&wv2)[j];
      acc.w += xv.w * ((const float*)&wv3)[j];
    }
  }

  float4 o;
  o.x = acc.x / (1.f + __expf(-acc.x));
  o.y = acc.y / (1.f + __expf(-acc.y));
  o.z = acc.z / (1.f + __expf(-acc.z));
  o.w = acc.w / (1.f + __expf(-acc.w));
  *(float4*)(xc + ((long)dir * MROWS + m) * DI + d) = o;
}

// ---------------------------------------------------------------------------
// Chunked parallel scan (3 passes) — unchanged from round 2.
// ---------------------------------------------------------------------------
__global__ __launch_bounds__(256)
void scan_p1(const float* __restrict__ dt, const float* __restrict__ dbc,
             const float* __restrict__ xc, const float* __restrict__ A_log,
             float* __restrict__ Pbuf, float* __restrict__ Ebuf)
{
  const int blk  = blockIdx.x;
  const int c    = blk & 15;
  const int dblk = (blk >> 4) & 7;
  const int b    = (blk >> 7) & 1;
  const int dir  = blk >> 8;
  const int d    = (dblk << 8) + threadIdx.x;

  const long row0 = (long)dir * MROWS + (long)b * LSEQ + (long)c * CL;
  const float* dtp = dt + row0 * DI + d;
  const float* xcp = xc + row0 * DI + d;
  const float* bc  = dbc + row0 * 96;

  float Av[DS];
  #pragma unroll
  for (int n = 0; n < DS; n++)
    Av[n] = -__expf(A_log[((long)dir * DI + d) * DS + n]);

  __shared__ float sB[CL][DS];
  #pragma unroll
  for (int i = 0; i < 4; i++) {
    const int e = threadIdx.x * 4 + i;
    sB[e >> 4][e & 15] = bc[(long)(e >> 4) * 96 + 64 + (e & 15)];
  }
  __syncthreads();

  float h[DS];
  #pragma unroll
  for (int n = 0; n < DS; n++) h[n] = 0.f;
  float sdt = 0.f;

  for (int li = 0; li < CL; li++) {
    const float dtv = dtp[(long)li * DI];
    const float xv  = xcp[(long)li * DI];
    const float u = dtv * xv;
    sdt += dtv;
    #pragma unroll
    for (int n = 0; n < DS; n++)
      h[n] = h[n] * __expf(dtv * Av[n]) + u * sB[li][n];
  }

  const long slot = ((long)((dir * 2 + b) * NCH + c)) * DS;
  #pragma unroll
  for (int n = 0; n < DS; n++) Ebuf[(slot + n) * DI + d] = h[n];
  #pragma unroll
  for (int n = 0; n < DS; n++) Pbuf[(slot + n) * DI + d] = __expf(Av[n] * sdt);
}

__global__ __launch_bounds__(256)
void scan_p2(float* __restrict__ Pbuf, const float* __restrict__ Ebuf)
{
  const int blk  = blockIdx.x;
  const int dblk = blk & 7;
  const int b    = (blk >> 3) & 1;
  const int dir  = blk >> 4;
  const int d    = (dblk << 8) + threadIdx.x;

  float h[DS];
  #pragma unroll
  for (int n = 0; n < DS; n++) h[n] = 0.f;

  for (int c = 0; c < NCH; c++) {
    const long slot = ((long)((dir * 2 + b) * NCH + c)) * DS;
    float p[DS], e[DS];
    #pragma unroll
    for (int n = 0; n < DS; n++) p[n] = Pbuf[(slot + n) * DI + d];
    #pragma unroll
    for (int n = 0; n < DS; n++) e[n] = Ebuf[(slot + n) * DI + d];
    #pragma unroll
    for (int n = 0; n < DS; n++) Pbuf[(slot + n) * DI + d] = h[n];
    #pragma unroll
    for (int n = 0; n < DS; n++) h[n] = p[n] * h[n] + e[n];
  }
}

__global__ __launch_bounds__(256)
void scan_p3(const float* __restrict__ dt, const float* __restrict__ dbc,
             float* __restrict__ xc, const float* __restrict__ xz,
             const float* __restrict__ A_log, const float* __restrict__ Dp,
             const float* __restrict__ Hbuf)
{
  const int blk  = blockIdx.x;
  const int c    = blk & 15;
  const int dblk = (blk >> 4) & 7;
  const int b    = (blk >> 7) & 1;
  const int dir  = blk >> 8;
  const int d    = (dblk << 8) + threadIdx.x;

  const long row0 = (long)dir * MROWS + (long)b * LSEQ + (long)c * CL;
  const float* dtp = dt + row0 * DI + d;
  float*       xcp = xc + row0 * DI + d;
  const float* zp  = xz + row0 * 4096 + DI + d;
  const float* bc  = dbc + row0 * 96;

  float Av[DS];
  #pragma unroll
  for (int n = 0; n < DS; n++)
    Av[n] = -__expf(A_log[((long)dir * DI + d) * DS + n]);
  const float Dd = Dp[(long)dir * DI + d];

  const long slot = ((long)((dir * 2 + b) * NCH + c)) * DS;
  float h[DS];
  #pragma unroll
  for (int n = 0; n < DS; n++) h[n] = Hbuf[(slot + n) * DI + d];

  __shared__ float sBC[CL][32];
  #pragma unroll
  for (int i = 0; i < 8; i++) {
    const int e = threadIdx.x * 8 + i;
    sBC[e >> 5][e & 31] = bc[(long)(e >> 5) * 96 + 64 + (e & 31)];
  }
  __syncthreads();

  for (int li = 0; li < CL; li++) {
    const float dtv = dtp[(long)li * DI];
    const float xv  = xcp[(long)li * DI];
    const float zv  = zp[(long)li * 4096];
    const float u = dtv * xv;
    float y = 0.f;
    #pragma unroll
    for (int n = 0; n < DS; n++) {
      const float dA = __expf(dtv * Av[n]);
      h[n] = h[n] * dA + u * sBC[li][n];
      y += h[n] * sBC[li][16 + n];
    }
    const float sig = 1.f / (1.f + __expf(-zv));
    xcp[(long)li * DI] = (y + xv * Dd) * (zv * sig);
  }
}

// ---------------------------------------------------------------------------
extern "C" void kernel_launch(void* const* d_in, const int* in_sizes, int n_in,
                              void* d_out, int out_size, void* d_ws, size_t ws_size,
                              hipStream_t stream)
{
  const float* x      = (const float*)d_in[0];
  const float* in_w   = (const float*)d_in[1];
  const float* conv_w = (const float*)d_in[2];
  const float* conv_b = (const float*)d_in[3];
  const float* xp_w   = (const float*)d_in[4];
  const float* dt_w   = (const float*)d_in[5];
  const float* dt_b   = (const float*)d_in[6];
  const float* A_log  = (const float*)d_in[7];
  const float* Dp     = (const float*)d_in[8];
  const float* out_w  = (const float*)d_in[9];
  const float* proj_w = (const float*)d_in[10];
  const float* proj_b = (const float*)d_in[11];
  float* out = (float*)d_out;

  // ---- workspace layout (floats), peak 149.5 MB via sequential aliasing ----
  const long M1 = 1024 * 1024;
  float* ws  = (float*)d_ws;
  float* xz   = ws;                    // 16M floats; z read until scan_p3
  float* xc   = xz  + 16 * M1;         // 8M
  float* dbc  = xc  + 8 * M1;          // 0.375M
  float* dt   = dbc + 393216;          // 8M; dead after p3
  float* regR = dt  + 8 * M1;          // 5M shared region
  // phase A (pre-G1): xb + in_wt in regR
  unsigned short* xb    = (unsigned short*)regR;              // 2M bf16
  unsigned short* in_wt = (unsigned short*)(regR + M1);       // 8M bf16
  // phase B (scan): Pbuf/Ebuf in regR
  float* Pbuf = regR;                  // 2M floats
  float* Ebuf = regR + 2 * M1;         // 2M floats
  // phase C (post-p3): ymulb in regR; owt/pwt over dead dt; catb over dead xz
  unsigned short* ymulb = (unsigned short*)regR;              // 8M bf16
  unsigned short* owt   = (unsigned short*)dt;                // 4M bf16
  unsigned short* pwt   = (unsigned short*)(dt + 2 * M1);     // 2M bf16
  unsigned short* catb  = (unsigned short*)xz;                // 4M bf16

  // convert x -> bf16
  hipLaunchKernelGGL(convert_bf16_k, dim3(2048), dim3(256), 0, stream, x, xb);
  // transpose-convert in_w: [2][1024][4096] -> [2][4096][1024] bf16
  hipLaunchKernelGGL(transpose_bf16_k, dim3(128, 32, 2), dim3(256), 0, stream,
                     in_w, (long)1024 * 4096, 1024, 4096, in_wt, (long)4096 * 1024);

  // G1: xz[dir] = (dir==1 ? reverse(x) : x) @ in_w[dir]   (bf16 MFMA)
  hipLaunchKernelGGL(HIP_KERNEL_NAME(bgemm<0>), dim3(32, 16, 2), dim3(256), 0, stream,
                     xb, (long)0, 1024, 1,
                     in_wt, (long)4096 * 1024,
                     (const float*)nullptr,
                     xz, (long)MROWS * 4096, 4096, 0, 0,
                     1024);

  // conv + SiLU
  hipLaunchKernelGGL(conv_silu_k, dim3(8192), dim3(256), 0, stream,
                     xz, xc, conv_w, conv_b);

  // G2: dbc = xc @ xp_w (fp32)
  hipLaunchKernelGGL(gemm32, dim3(3, 64, 2), dim3(256), 0, stream,
                     xc, (long)MROWS * DI, DI,
                     xp_w, (long)DI * 96,
                     dbc, (long)MROWS * 96, 96,
                     96, DI);

  // G3: dt = softplus(dbc[:, :64] @ dt_w + dt_b) (fp32)
  hipLaunchKernelGGL(HIP_KERNEL_NAME(gemm128<2>), dim3(16, 16, 2), dim3(256), 0, stream,
                     dbc, (long)MROWS * 96, 96, 0,
                     dt_w, (long)DTR * DI,
                     dt_b, DI,
                     dt, (long)MROWS * DI, DI, 0, 0,
                     DI, DTR);

  // chunked parallel scan
  hipLaunchKernelGGL(scan_p1, dim3(512), dim3(256), 0, stream,
                     dt, dbc, xc, A_log, Pbuf, Ebuf);
  hipLaunchKernelGGL(scan_p2, dim3(32), dim3(256), 0, stream,
                     Pbuf, Ebuf);
  hipLaunchKernelGGL(scan_p3, dim3(512), dim3(256), 0, stream,
                     dt, dbc, xc, xz, A_log, Dp, Pbuf);

  // ymul (in xc) -> bf16; weights for G4/G5 -> transposed bf16 (dt now dead)
  hipLaunchKernelGGL(convert_bf16_k, dim3(8192), dim3(256), 0, stream, xc, ymulb);
  hipLaunchKernelGGL(transpose_bf16_k, dim3(32, 64, 2), dim3(256), 0, stream,
                     out_w, (long)2048 * 1024, 2048, 1024, owt, (long)1024 * 2048);
  hipLaunchKernelGGL(transpose_bf16_k, dim3(32, 64, 1), dim3(256), 0, stream,
                     proj_w, (long)0, 2048, 1024, pwt, (long)0);

  // G4: catb[:, dir*1024+:] = ymul @ out_w[dir]  (rows reversed for dir 1, bf16 out)
  hipLaunchKernelGGL(HIP_KERNEL_NAME(bgemm<2>), dim3(8, 16, 2), dim3(256), 0, stream,
                     ymulb, (long)MROWS * DI, DI, 0,
                     owt, (long)1024 * 2048,
                     (const float*)nullptr,
                     catb, (long)0, 2048, 1, 1024,
                     2048);

  // G5: out = catb @ proj_w + proj_b  (fp32 out)
  hipLaunchKernelGGL(HIP_KERNEL_NAME(bgemm<1>), dim3(8, 16, 1), dim3(256), 0, stream,
                     catb, (long)0, 2048, 0,
                     pwt, (long)0,
                     proj_b,
                     out, (long)0, 1024, 0, 0,
                     2048);
}

// Round 4
// 366.317 us; speedup vs baseline: 4.9390x; 1.1782x over previous
//
#include <hip/hip_runtime.h>
#include <hip/hip_bf16.h>

#define B_    2
#define LSEQ  1024
#define DM    1024
#define DI    2048
#define DTR   64
#define DS    16
#define MROWS 2048   // B_*LSEQ rows per direction
#define NCH   16     // scan chunks per sequence
#define CL    64     // steps per chunk
#define KSPL  16     // split-K factor for G2

typedef __bf16 bf16x8 __attribute__((ext_vector_type(8)));
typedef short  s16x8  __attribute__((ext_vector_type(8)));
typedef float  f32x4  __attribute__((ext_vector_type(4)));

typedef __attribute__((address_space(1))) const unsigned int g_u32;
typedef __attribute__((address_space(3))) unsigned int l_u32;

__device__ __forceinline__ unsigned short f2bf(float f) {
  unsigned int u = __builtin_bit_cast(unsigned int, f);
  u += 0x7fffu + ((u >> 16) & 1u);           // RNE
  return (unsigned short)(u >> 16);
}

__device__ __forceinline__ void gload16(void* lds, const void* g) {
  __builtin_amdgcn_global_load_lds((g_u32*)g, (l_u32*)lds, 16, 0, 0);
}

__device__ __forceinline__ f32x4 mfma_bf16_16x16x32(s16x8 a, s16x8 b, f32x4 c) {
  return __builtin_amdgcn_mfma_f32_16x16x32_bf16(
      __builtin_bit_cast(bf16x8, a), __builtin_bit_cast(bf16x8, b), c, 0, 0, 0);
}

__device__ __forceinline__ float softplus_f(float x) {
  return fmaxf(x, 0.f) + log1pf(__expf(-fabsf(x)));
}

// ---------------------------------------------------------------------------
// bf16 MFMA GEMM, 128x128 tile, BK=32, 4 waves (m97 structure).
// A: bf16 row-major [M][K]; Bt: bf16 [N][K] (transposed weights).
// EPI: 0 = f32 store, 1 = f32 store + bias, 2 = bf16 store (revC + colOff)
// ---------------------------------------------------------------------------
template<int EPI>
__global__ __launch_bounds__(256)
void bgemm(const unsigned short* __restrict__ A, long sAd, int lda, int revA,
           const unsigned short* __restrict__ Bt, long sBd,
           const float* __restrict__ bias,
           void* __restrict__ C, long sCd, int ldc, int revC, int colOffDir,
           int K)
{
  const int dir = blockIdx.z;
  A  += (long)dir * sAd;
  Bt += (long)dir * sBd;

  const int m0 = blockIdx.y * 128;
  const int n0 = blockIdx.x * 128;

  __shared__ __align__(16) unsigned short sA[128 * 32];
  __shared__ __align__(16) unsigned short sB[128 * 32];

  const int t    = threadIdx.x;
  const int wave = t >> 6;
  const int lane = t & 63;
  const int l15  = lane & 15;
  const int l4   = lane >> 4;
  const int wr   = wave >> 1;
  const int wc   = wave & 1;

  f32x4 acc[4][4];
  #pragma unroll
  for (int i = 0; i < 4; i++)
    #pragma unroll
    for (int j = 0; j < 4; j++)
      acc[i][j] = f32x4{0.f, 0.f, 0.f, 0.f};

  for (int k0 = 0; k0 < K; k0 += 32) {
    #pragma unroll
    for (int i = 0; i < 2; i++) {
      const int cb = (wave * 2 + i) * 64;
      const int ch = cb + lane;
      const int row = ch >> 2, kk = (ch & 3) << 3;
      const int mm = m0 + row;
      const int mr = (revA && dir) ? ((mm & ~(LSEQ - 1)) | (LSEQ - 1 - (mm & (LSEQ - 1)))) : mm;
      gload16(sA + (long)cb * 8, A + (long)mr * lda + k0 + kk);
    }
    #pragma unroll
    for (int i = 0; i < 2; i++) {
      const int cb = (wave * 2 + i) * 64;
      const int ch = cb + lane;
      const int n = ch >> 2, kk = (ch & 3) << 3;
      gload16(sB + (long)cb * 8, Bt + (long)(n0 + n) * K + k0 + kk);
    }
    __syncthreads();

    s16x8 af[4], bf[4];
    #pragma unroll
    for (int mi = 0; mi < 4; mi++)
      af[mi] = *(const s16x8*)(sA + ((wr * 64 + mi * 16 + l15) * 32 + l4 * 8));
    #pragma unroll
    for (int ni = 0; ni < 4; ni++)
      bf[ni] = *(const s16x8*)(sB + ((wc * 64 + ni * 16 + l15) * 32 + l4 * 8));
    #pragma unroll
    for (int mi = 0; mi < 4; mi++)
      #pragma unroll
      for (int ni = 0; ni < 4; ni++)
        acc[mi][ni] = mfma_bf16_16x16x32(af[mi], bf[ni], acc[mi][ni]);
    __syncthreads();
  }

  const int colOff = dir * colOffDir;
  float*          Cf = (float*)C + (long)dir * sCd;
  unsigned short* Cb = (unsigned short*)C + (long)dir * sCd;
  #pragma unroll
  for (int mi = 0; mi < 4; mi++) {
    #pragma unroll
    for (int r = 0; r < 4; r++) {
      const int mm = m0 + wr * 64 + mi * 16 + (l4 << 2) + r;
      const int mr = (revC && dir) ? ((mm & ~(LSEQ - 1)) | (LSEQ - 1 - (mm & (LSEQ - 1)))) : mm;
      #pragma unroll
      for (int ni = 0; ni < 4; ni++) {
        const int col = n0 + wc * 64 + ni * 16 + l15;
        float v = acc[mi][ni][r];
        if (EPI == 1) v += bias[col];
        if (EPI == 2) Cb[(long)mr * ldc + colOff + col] = f2bf(v);
        else          Cf[(long)mr * ldc + colOff + col] = v;
      }
    }
  }
}

// ---------------------------------------------------------------------------
// G2: bf16 MFMA split-K GEMM for dbc = xcb @ xp_w^T.  Tile 128 x 96,
// 4 waves (2x2, wave tile 64x48), K=128 per block (4 x BK32), KSPL blocks in K.
// Partials to dbc4[ks][4096][96] f32 (deterministic; reduced afterwards).
// ---------------------------------------------------------------------------
__global__ __launch_bounds__(256)
void bgemm96(const unsigned short* __restrict__ A,     // [4096][2048] bf16
             const unsigned short* __restrict__ Bt,    // [2][96][2048] bf16
             float* __restrict__ dbc4)                 // [KSPL][4096][96]
{
  const int ks  = blockIdx.x;
  const int m0  = blockIdx.y * 128;
  const int dir = blockIdx.z;
  const int kbase = ks * (2048 / KSPL);

  const unsigned short* Ad  = A  + (long)dir * MROWS * DI;
  const unsigned short* Btd = Bt + (long)dir * 96 * DI;

  __shared__ __align__(16) unsigned short sA[128 * 32];  // 8KB
  __shared__ __align__(16) unsigned short sB[96 * 32];   // 6KB

  const int t    = threadIdx.x;
  const int wave = t >> 6;
  const int lane = t & 63;
  const int l15  = lane & 15;
  const int l4   = lane >> 4;
  const int wr   = wave >> 1;
  const int wc   = wave & 1;

  f32x4 acc[4][3];
  #pragma unroll
  for (int i = 0; i < 4; i++)
    #pragma unroll
    for (int j = 0; j < 3; j++)
      acc[i][j] = f32x4{0.f, 0.f, 0.f, 0.f};

  for (int k0 = 0; k0 < 2048 / KSPL; k0 += 32) {
    // stage A: 512 x 16B chunks
    #pragma unroll
    for (int i = 0; i < 2; i++) {
      const int cb = (wave * 2 + i) * 64;
      const int ch = cb + lane;
      const int row = ch >> 2, kk = (ch & 3) << 3;
      gload16(sA + (long)cb * 8, Ad + (long)(m0 + row) * DI + kbase + k0 + kk);
    }
    // stage B: 384 x 16B chunks
    {
      const int cb = wave * 64;
      const int ch = cb + lane;
      const int n = ch >> 2, kk = (ch & 3) << 3;
      gload16(sB + (long)cb * 8, Btd + (long)n * DI + kbase + k0 + kk);
    }
    if (wave < 2) {
      const int cb = 256 + wave * 64;
      const int ch = cb + lane;
      const int n = ch >> 2, kk = (ch & 3) << 3;
      gload16(sB + (long)cb * 8, Btd + (long)n * DI + kbase + k0 + kk);
    }
    __syncthreads();

    s16x8 af[4], bf[3];
    #pragma unroll
    for (int mi = 0; mi < 4; mi++)
      af[mi] = *(const s16x8*)(sA + ((wr * 64 + mi * 16 + l15) * 32 + l4 * 8));
    #pragma unroll
    for (int ni = 0; ni < 3; ni++)
      bf[ni] = *(const s16x8*)(sB + ((wc * 48 + ni * 16 + l15) * 32 + l4 * 8));
    #pragma unroll
    for (int mi = 0; mi < 4; mi++)
      #pragma unroll
      for (int ni = 0; ni < 3; ni++)
        acc[mi][ni] = mfma_bf16_16x16x32(af[mi], bf[ni], acc[mi][ni]);
    __syncthreads();
  }

  float* outp = dbc4 + (long)ks * 4096 * 96;
  #pragma unroll
  for (int mi = 0; mi < 4; mi++) {
    #pragma unroll
    for (int r = 0; r < 4; r++) {
      const long grow = (long)dir * MROWS + m0 + wr * 64 + mi * 16 + (l4 << 2) + r;
      #pragma unroll
      for (int ni = 0; ni < 3; ni++) {
        const int col = wc * 48 + ni * 16 + l15;
        outp[grow * 96 + col] = acc[mi][ni][r];
      }
    }
  }
}

// reduce KSPL split-K partials into dbc
__global__ __launch_bounds__(256)
void reduce_k(const float* __restrict__ dbc4, float* __restrict__ dbc)
{
  const long i = ((long)blockIdx.x * 256 + threadIdx.x) << 2;   // 4096*96/4 threads
  f32x4 s = *(const f32x4*)(dbc4 + i);
  #pragma unroll
  for (int ks = 1; ks < KSPL; ks++) {
    f32x4 v = *(const f32x4*)(dbc4 + (long)ks * 4096 * 96 + i);
    s.x += v.x; s.y += v.y; s.z += v.z; s.w += v.w;
  }
  *(f32x4*)(dbc + i) = s;
}

// ---------------------------------------------------------------------------
// fp32 -> bf16 elementwise convert
// ---------------------------------------------------------------------------
__global__ __launch_bounds__(256)
void convert_bf16_k(const float* __restrict__ src, unsigned short* __restrict__ dst)
{
  const long i = ((long)blockIdx.x * 256 + threadIdx.x) << 2;
  const float4 v = *(const float4*)(src + i);
  ushort4 o;
  o.x = f2bf(v.x); o.y = f2bf(v.y); o.z = f2bf(v.z); o.w = f2bf(v.w);
  *(ushort4*)(dst + i) = o;
}

// ---------------------------------------------------------------------------
// fp32 [R][C] -> bf16 [C][R] transpose-convert, 32x32 tiles.
// ---------------------------------------------------------------------------
__global__ __launch_bounds__(256)
void transpose_bf16_k(const float* __restrict__ src, long sSd, int R, int C,
                      unsigned short* __restrict__ dst, long sDd)
{
  const int dir = blockIdx.z;
  src += (long)dir * sSd;
  dst += (long)dir * sDd;
  const int c0 = blockIdx.x * 32;
  const int r0 = blockIdx.y * 32;
  __shared__ float tile[32][33];
  const int t = threadIdx.x;
  const int lr = t >> 3, lc = (t & 7) << 2;
  const float4 v = *(const float4*)(src + (long)(r0 + lr) * C + c0 + lc);
  tile[lr][lc + 0] = v.x; tile[lr][lc + 1] = v.y;
  tile[lr][lc + 2] = v.z; tile[lr][lc + 3] = v.w;
  __syncthreads();
  const int oc = t >> 3, orr = (t & 7) << 2;
  ushort4 o;
  o.x = f2bf(tile[orr + 0][oc]);
  o.y = f2bf(tile[orr + 1][oc]);
  o.z = f2bf(tile[orr + 2][oc]);
  o.w = f2bf(tile[orr + 3][oc]);
  *(ushort4*)(dst + (long)(c0 + oc) * R + r0 + orr) = o;
}

// ---------------------------------------------------------------------------
// fp32 GEMM kept for G3 (dt projection, K=64)
// ---------------------------------------------------------------------------
template<int ACT>
__global__ __launch_bounds__(256)
void gemm128(const float* __restrict__ A, long sAd, int lda, int revA,
             const float* __restrict__ W, long sWd,
             const float* __restrict__ bias, int sBd,
             float* __restrict__ C, long sCd, int ldc, int revC, int colOffDir,
             int N, int K)
{
  const int dir = blockIdx.z;
  A += (long)dir * sAd;
  W += (long)dir * sWd;
  C += (long)dir * sCd;
  const float* bp = bias ? (bias + (long)dir * sBd) : nullptr;

  const int m0 = blockIdx.y * 128;
  const int n0 = blockIdx.x * 128;

  __shared__ float sA[16][132];
  __shared__ float sB[16][132];

  const int t  = threadIdx.x;
  const int tx = t & 15, ty = t >> 4;
  const int ar = t >> 2, ak = (t & 3) << 2;
  const int wrr = t >> 5, wcc = (t & 31) << 2;

  float acc[8][8];
  #pragma unroll
  for (int i = 0; i < 8; i++)
    #pragma unroll
    for (int j = 0; j < 8; j++) acc[i][j] = 0.f;

  for (int k0 = 0; k0 < K; k0 += 16) {
    #pragma unroll
    for (int i = 0; i < 2; i++) {
      const int mm = m0 + ar + (i << 6);
      const int mr = (revA && dir) ? ((mm & ~(LSEQ - 1)) | (LSEQ - 1 - (mm & (LSEQ - 1)))) : mm;
      const float4 v = *(const float4*)(A + (long)mr * lda + (k0 + ak));
      sA[ak + 0][ar + (i << 6)] = v.x;
      sA[ak + 1][ar + (i << 6)] = v.y;
      sA[ak + 2][ar + (i << 6)] = v.z;
      sA[ak + 3][ar + (i << 6)] = v.w;
    }
    #pragma unroll
    for (int i = 0; i < 2; i++) {
      const int kk = k0 + wrr + (i << 3);
      const float4 v = *(const float4*)(W + (long)kk * N + (n0 + wcc));
      *(float4*)&sB[wrr + (i << 3)][wcc] = v;
    }
    __syncthreads();

    #pragma unroll
    for (int kk = 0; kk < 16; kk++) {
      float a[8], b[8];
      *(float4*)&a[0] = *(const float4*)&sA[kk][(ty << 3) + 0];
      *(float4*)&a[4] = *(const float4*)&sA[kk][(ty << 3) + 4];
      *(float4*)&b[0] = *(const float4*)&sB[kk][(tx << 3) + 0];
      *(float4*)&b[4] = *(const float4*)&sB[kk][(tx << 3) + 4];
      #pragma unroll
      for (int i = 0; i < 8; i++)
        #pragma unroll
        for (int j = 0; j < 8; j++)
          acc[i][j] += a[i] * b[j];
    }
    __syncthreads();
  }

  const int colOff = dir * colOffDir;
  #pragma unroll
  for (int i = 0; i < 8; i++) {
    const int mm = m0 + (ty << 3) + i;
    const int mr = (revC && dir) ? ((mm & ~(LSEQ - 1)) | (LSEQ - 1 - (mm & (LSEQ - 1)))) : mm;
    float* crow = C + (long)mr * ldc + colOff + n0 + (tx << 3);
    float v[8];
    #pragma unroll
    for (int j = 0; j < 8; j++) {
      float vv = acc[i][j];
      if (ACT >= 1) vv += bp[n0 + (tx << 3) + j];
      if (ACT == 2) vv = softplus_f(vv);
      v[j] = vv;
    }
    *(float4*)(crow + 0) = make_float4(v[0], v[1], v[2], v[3]);
    *(float4*)(crow + 4) = make_float4(v[4], v[5], v[6], v[7]);
  }
}

// ---------------------------------------------------------------------------
// Depthwise causal conv (D_CONV=4) + bias + SiLU; emits fp32 xc and bf16 xcb.
// ---------------------------------------------------------------------------
__global__ __launch_bounds__(256)
void conv_silu_k(const float* __restrict__ xz, float* __restrict__ xc,
                 unsigned short* __restrict__ xcb,
                 const float* __restrict__ cw, const float* __restrict__ cb)
{
  const long idx = (long)blockIdx.x * blockDim.x + threadIdx.x;
  const int d4  = (int)(idx & 511);
  const int m   = (int)((idx >> 9) & 2047);
  const int dir = (int)(idx >> 20);
  const int l = m & (LSEQ - 1);
  const int d = d4 << 2;

  const float* xzp = xz + ((long)dir * MROWS + m) * 4096 + d;
  const float* w   = cw + ((long)dir * DI + d) * 4;

  float4 wv0 = *(const float4*)(w + 0);
  float4 wv1 = *(const float4*)(w + 4);
  float4 wv2 = *(const float4*)(w + 8);
  float4 wv3 = *(const float4*)(w + 12);

  float4 acc = *(const float4*)(cb + (long)dir * DI + d);

  #pragma unroll
  for (int j = 0; j < 4; j++) {
    const int lj = l - 3 + j;
    if (lj >= 0) {
      const float4 xv = *(const float4*)(xzp + (long)(j - 3) * 4096);
      acc.x += xv.x * ((const float*)&wv0)[j];
      acc.y += xv.y * ((const float*)&wv1)[j];
      acc.z += xv.z * ((const float*)&wv2)[j];
      acc.w += xv.w * ((const float*)&wv3)[j];
    }
  }

  float4 o;
  o.x = acc.x / (1.f + __expf(-acc.x));
  o.y = acc.y / (1.f + __expf(-acc.y));
  o.z = acc.z / (1.f + __expf(-acc.z));
  o.w = acc.w / (1.f + __expf(-acc.w));
  const long base = ((long)dir * MROWS + m) * DI + d;
  *(float4*)(xc + base) = o;
  ushort4 ob;
  ob.x = f2bf(o.x); ob.y = f2bf(o.y); ob.z = f2bf(o.z); ob.w = f2bf(o.w);
  *(ushort4*)(xcb + base) = ob;
}

// ---------------------------------------------------------------------------
// Chunked parallel scan (3 passes)
// ---------------------------------------------------------------------------
__global__ __launch_bounds__(256)
void scan_p1(const float* __restrict__ dt, const float* __restrict__ dbc,
             const float* __restrict__ xc, const float* __restrict__ A_log,
             float* __restrict__ Pbuf, float* __restrict__ Ebuf)
{
  const int blk  = blockIdx.x;
  const int c    = blk & 15;
  const int dblk = (blk >> 4) & 7;
  const int b    = (blk >> 7) & 1;
  const int dir  = blk >> 8;
  const int d    = (dblk << 8) + threadIdx.x;

  const long row0 = (long)dir * MROWS + (long)b * LSEQ + (long)c * CL;
  const float* dtp = dt + row0 * DI + d;
  const float* xcp = xc + row0 * DI + d;
  const float* bc  = dbc + row0 * 96;

  float Av[DS];
  #pragma unroll
  for (int n = 0; n < DS; n++)
    Av[n] = -__expf(A_log[((long)dir * DI + d) * DS + n]);

  __shared__ float sB[CL][DS];
  #pragma unroll
  for (int i = 0; i < 4; i++) {
    const int e = threadIdx.x * 4 + i;
    sB[e >> 4][e & 15] = bc[(long)(e >> 4) * 96 + 64 + (e & 15)];
  }
  __syncthreads();

  float h[DS];
  #pragma unroll
  for (int n = 0; n < DS; n++) h[n] = 0.f;
  float sdt = 0.f;

  for (int li = 0; li < CL; li++) {
    const float dtv = dtp[(long)li * DI];
    const float xv  = xcp[(long)li * DI];
    const float u = dtv * xv;
    sdt += dtv;
    #pragma unroll
    for (int n = 0; n < DS; n++)
      h[n] = h[n] * __expf(dtv * Av[n]) + u * sB[li][n];
  }

  const long slot = ((long)((dir * 2 + b) * NCH + c)) * DS;
  #pragma unroll
  for (int n = 0; n < DS; n++) Ebuf[(slot + n) * DI + d] = h[n];
  #pragma unroll
  for (int n = 0; n < DS; n++) Pbuf[(slot + n) * DI + d] = __expf(Av[n] * sdt);
}

__global__ __launch_bounds__(256)
void scan_p2(float* __restrict__ Pbuf, const float* __restrict__ Ebuf)
{
  const int blk  = blockIdx.x;
  const int dblk = blk & 7;
  const int b    = (blk >> 3) & 1;
  const int dir  = blk >> 4;
  const int d    = (dblk << 8) + threadIdx.x;

  float h[DS];
  #pragma unroll
  for (int n = 0; n < DS; n++) h[n] = 0.f;

  for (int c = 0; c < NCH; c++) {
    const long slot = ((long)((dir * 2 + b) * NCH + c)) * DS;
    float p[DS], e[DS];
    #pragma unroll
    for (int n = 0; n < DS; n++) p[n] = Pbuf[(slot + n) * DI + d];
    #pragma unroll
    for (int n = 0; n < DS; n++) e[n] = Ebuf[(slot + n) * DI + d];
    #pragma unroll
    for (int n = 0; n < DS; n++) Pbuf[(slot + n) * DI + d] = h[n];
    #pragma unroll
    for (int n = 0; n < DS; n++) h[n] = p[n] * h[n] + e[n];
  }
}

// pass 3: replay + fused D-skip + SiLU(z) gate, writes bf16 ymul directly.
__global__ __launch_bounds__(256)
void scan_p3(const float* __restrict__ dt, const float* __restrict__ dbc,
             const float* __restrict__ xc, const float* __restrict__ xz,
             const float* __restrict__ A_log, const float* __restrict__ Dp,
             const float* __restrict__ Hbuf, unsigned short* __restrict__ ymul)
{
  const int blk  = blockIdx.x;
  const int c    = blk & 15;
  const int dblk = (blk >> 4) & 7;
  const int b    = (blk >> 7) & 1;
  const int dir  = blk >> 8;
  const int d    = (dblk << 8) + threadIdx.x;

  const long row0 = (long)dir * MROWS + (long)b * LSEQ + (long)c * CL;
  const float* dtp = dt + row0 * DI + d;
  const float* xcp = xc + row0 * DI + d;
  const float* zp  = xz + row0 * 4096 + DI + d;
  unsigned short* ymp = ymul + row0 * DI + d;
  const float* bc  = dbc + row0 * 96;

  float Av[DS];
  #pragma unroll
  for (int n = 0; n < DS; n++)
    Av[n] = -__expf(A_log[((long)dir * DI + d) * DS + n]);
  const float Dd = Dp[(long)dir * DI + d];

  const long slot = ((long)((dir * 2 + b) * NCH + c)) * DS;
  float h[DS];
  #pragma unroll
  for (int n = 0; n < DS; n++) h[n] = Hbuf[(slot + n) * DI + d];

  __shared__ float sBC[CL][32];
  #pragma unroll
  for (int i = 0; i < 8; i++) {
    const int e = threadIdx.x * 8 + i;
    sBC[e >> 5][e & 31] = bc[(long)(e >> 5) * 96 + 64 + (e & 31)];
  }
  __syncthreads();

  for (int li = 0; li < CL; li++) {
    const float dtv = dtp[(long)li * DI];
    const float xv  = xcp[(long)li * DI];
    const float zv  = zp[(long)li * 4096];
    const float u = dtv * xv;
    float y = 0.f;
    #pragma unroll
    for (int n = 0; n < DS; n++) {
      const float dA = __expf(dtv * Av[n]);
      h[n] = h[n] * dA + u * sBC[li][n];
      y += h[n] * sBC[li][16 + n];
    }
    const float sig = 1.f / (1.f + __expf(-zv));
    ymp[(long)li * DI] = f2bf((y + xv * Dd) * (zv * sig));
  }
}

// ---------------------------------------------------------------------------
extern "C" void kernel_launch(void* const* d_in, const int* in_sizes, int n_in,
                              void* d_out, int out_size, void* d_ws, size_t ws_size,
                              hipStream_t stream)
{
  const float* x      = (const float*)d_in[0];
  const float* in_w   = (const float*)d_in[1];
  const float* conv_w = (const float*)d_in[2];
  const float* conv_b = (const float*)d_in[3];
  const float* xp_w   = (const float*)d_in[4];
  const float* dt_w   = (const float*)d_in[5];
  const float* dt_b   = (const float*)d_in[6];
  const float* A_log  = (const float*)d_in[7];
  const float* Dp     = (const float*)d_in[8];
  const float* out_w  = (const float*)d_in[9];
  const float* proj_w = (const float*)d_in[10];
  const float* proj_b = (const float*)d_in[11];
  float* out = (float*)d_out;

  // ---- workspace layout (floats), peak 161.5 MB (validated in round 1) ----
  const long M1 = 1024 * 1024;
  float* ws   = (float*)d_ws;
  float* xz   = ws;                    // 16M floats (z-part read until p3)
  float* xc   = xz  + 16 * M1;         // 8M  (conv out, fp32, scan input)
  float* dbc  = xc  + 8 * M1;          // 0.375M
  float* dt   = dbc + 393216;          // 8M  (dead after p3)
  float* regR = dt  + 8 * M1;          // 8M shared region -> total 40.375M
  // phase A (pre-G1): xb + in_wt
  unsigned short* xb    = (unsigned short*)regR;                 // 1M floats
  unsigned short* in_wt = (unsigned short*)(regR + M1);          // 4M floats
  // phase B (G2): dbc4 partials + xpwt
  float*          dbc4  = regR;                                  // 6.29M floats
  unsigned short* xpwt  = (unsigned short*)(regR + 6600 * 1024); // 0.19M floats
  // phase C (scan): Pbuf/Ebuf at regR, ymulb above them
  float* Pbuf = regR;                       // 2M floats
  float* Ebuf = regR + 2 * M1;              // 2M floats
  unsigned short* ymulb = (unsigned short*)(regR + 4 * M1);      // 4M floats
  // phase D (post-p3): owt/pwt over dead dt; catb over dead xz
  unsigned short* owt  = (unsigned short*)dt;                    // 2M floats
  unsigned short* pwt  = (unsigned short*)(dt + 2 * M1);         // 1M floats
  unsigned short* catb = (unsigned short*)xz;                    // 2M floats
  // bf16 copy of conv output for G2 (own slot, lives past scan start: none needed after G2)
  unsigned short* xcb  = (unsigned short*)(dt + 4 * M1);         // 4M floats? NO - dt live.
  // xcb must not overlap live dt/regR-phaseB: place over xb/in_wt slot is regR (dbc4)...
  // -> use dedicated aliasing: xcb lives only conv->G2; in that window regR holds dbc4(0..6.29M)
  //    and xpwt(6.6M..6.8M). Free regR sub-range: 6.8M..8M = 1.2M floats — too small (needs 4M).
  //    dt is written by G3 AFTER G2 -> dt region is FREE during conv->G2. Use it.
  xcb = (unsigned short*)dt;

  // xp_w transpose-convert (independent; region free until G2's dbc4 write... xpwt slot)
  hipLaunchKernelGGL(transpose_bf16_k, dim3(3, 64, 2), dim3(256), 0, stream,
                     xp_w, (long)DI * 96, DI, 96, xpwt, (long)96 * DI);
  // convert x -> bf16; transpose in_w
  hipLaunchKernelGGL(convert_bf16_k, dim3(2048), dim3(256), 0, stream, x, xb);
  hipLaunchKernelGGL(transpose_bf16_k, dim3(128, 32, 2), dim3(256), 0, stream,
                     in_w, (long)1024 * 4096, 1024, 4096, in_wt, (long)4096 * 1024);

  // G1: xz[dir] = (dir==1 ? reverse(x) : x) @ in_w[dir]   (bf16 MFMA)
  hipLaunchKernelGGL(HIP_KERNEL_NAME(bgemm<0>), dim3(32, 16, 2), dim3(256), 0, stream,
                     xb, (long)0, 1024, 1,
                     in_wt, (long)4096 * 1024,
                     (const float*)nullptr,
                     xz, (long)MROWS * 4096, 4096, 0, 0,
                     1024);

  // conv + SiLU -> xc (f32) + xcb (bf16, in dt region — dt written later by G3)
  hipLaunchKernelGGL(conv_silu_k, dim3(8192), dim3(256), 0, stream,
                     xz, xc, xcb, conv_w, conv_b);

  // G2: dbc4 partials = xcb @ xpwt^T (split-K), then reduce -> dbc
  hipLaunchKernelGGL(bgemm96, dim3(KSPL, 16, 2), dim3(256), 0, stream,
                     xcb, xpwt, dbc4);
  hipLaunchKernelGGL(reduce_k, dim3(384), dim3(256), 0, stream, dbc4, dbc);

  // G3: dt = softplus(dbc[:, :64] @ dt_w + dt_b)  (fp32; overwrites xcb region)
  hipLaunchKernelGGL(HIP_KERNEL_NAME(gemm128<2>), dim3(16, 16, 2), dim3(256), 0, stream,
                     dbc, (long)MROWS * 96, 96, 0,
                     dt_w, (long)DTR * DI,
                     dt_b, DI,
                     dt, (long)MROWS * DI, DI, 0, 0,
                     DI, DTR);

  // chunked parallel scan; p3 writes bf16 ymulb directly
  hipLaunchKernelGGL(scan_p1, dim3(512), dim3(256), 0, stream,
                     dt, dbc, xc, A_log, Pbuf, Ebuf);
  hipLaunchKernelGGL(scan_p2, dim3(32), dim3(256), 0, stream,
                     Pbuf, Ebuf);
  hipLaunchKernelGGL(scan_p3, dim3(512), dim3(256), 0, stream,
                     dt, dbc, xc, xz, A_log, Dp, Pbuf, ymulb);

  // weights for G4/G5 -> transposed bf16 (dt region dead after p3)
  hipLaunchKernelGGL(transpose_bf16_k, dim3(32, 64, 2), dim3(256), 0, stream,
                     out_w, (long)2048 * 1024, 2048, 1024, owt, (long)1024 * 2048);
  hipLaunchKernelGGL(transpose_bf16_k, dim3(32, 64, 1), dim3(256), 0, stream,
                     proj_w, (long)0, 2048, 1024, pwt, (long)0);

  // G4: catb[:, dir*1024+:] = ymul @ out_w[dir]  (rows reversed for dir 1, bf16 out)
  hipLaunchKernelGGL(HIP_KERNEL_NAME(bgemm<2>), dim3(8, 16, 2), dim3(256), 0, stream,
                     ymulb, (long)MROWS * DI, DI, 0,
                     owt, (long)1024 * 2048,
                     (const float*)nullptr,
                     catb, (long)0, 2048, 1, 1024,
                     2048);

  // G5: out = catb @ proj_w + proj_b  (fp32 out)
  hipLaunchKernelGGL(HIP_KERNEL_NAME(bgemm<1>), dim3(8, 16, 1), dim3(256), 0, stream,
                     catb, (long)0, 2048, 0,
                     pwt, (long)0,
                     proj_b,
                     out, (long)0, 1024, 0, 0,
                     2048);
}